// Round 6
// baseline (84.138 us; speedup 1.0000x reference)
//
#include <hip/hip_runtime.h>
#include <cfloat>

#define TPB 256
#define BKT 32768                 // buckets per side (2048 per unit over [-8,8))
#define SLOTS 16                  // floats per bucket = one 64B line
#define OVCAP 4096                // overflow capacity per side (expected 0 used)
#define RLO -8.0f
#define RSCALE (BKT / 16.0f)      // exact power of two
#define ALPHA 0.5f

// ---- workspace layout (uint words) -------------------------------------
// zeroed by ONE hipMemsetAsync: cnt | bm1 | bm2 | ovc | done | arrive
#define CNT_OFF   0                         // cnt[2*BKT]
#define BM1_OFF   (2 * BKT)                 // 2*1024 words (gated atomicOr)
#define BM2_OFF   (BM1_OFF + 2048)          // 2*32 words (gated atomicOr)
#define OVC_OFF   (BM2_OFF + 64)            // 2 words
#define DONE_OFF  (OVC_OFF + 2)             // 1 word (last-block fold counter)
#define ARR_OFF   (DONE_OFF + 1)            // 1 word (build->query barrier)
#define ZERO_WORDS (ARR_OFF + 1)
// not zeroed (reads gated by cnt / ovc):
#define SLOTS_OFF (((ZERO_WORDS) + 63) & ~63)   // floats, 2*BKT*SLOTS (64B-aligned)
#define OVF_OFF   (SLOTS_OFF + 2 * BKT * SLOTS) // floats, 2*OVCAP

// Monotone non-decreasing (fl(v+8) monotone, *2048 exact pow2, trunc+clamp
// monotone) => bucket(u) < bucket(w) implies u < w.
__device__ __forceinline__ int bucket_of(float v) {
    int b = (int)((v - RLO) * RSCALE);
    return min(max(b, 0), BKT - 1);
}

// ---- build one element: histogram + slot scatter + GATED occupancy bits.
// cnt atomicAdd ~4 ops/bucket (contention-free). bm1 atomicOr only when
// pos==0 (<=32 ops/word); bm2 atomicOr only on bm1 word 0->nonzero
// (<=32 ops/word). R2 lesson: ungated bm2 serialized ~3100 ops = 90+ us.
__device__ __forceinline__ void build_point(float v, int side,
                                            unsigned* __restrict__ ws) {
    const int b = bucket_of(v);
    const unsigned pos = atomicAdd(ws + CNT_OFF + side * BKT + b, 1u);
    if (pos < SLOTS) {
        ((float*)(ws + SLOTS_OFF))[((size_t)(side * BKT + b)) * SLOTS + pos] = v;
    } else {
        const unsigned o = atomicAdd(ws + OVC_OFF + side, 1u);
        if (o < OVCAP) ((float*)(ws + OVF_OFF))[side * OVCAP + o] = v;
    }
    if (pos == 0) {
        const int W = b >> 5;
        const unsigned old = atomicOr(ws + BM1_OFF + side * 1024 + W, 1u << (b & 31));
        if (old == 0)
            atomicOr(ws + BM2_OFF + side * 32 + (W >> 5), 1u << (W & 31));
    }
}

// Previous/next nonempty bucket via 2-level bitmap (bounded, no bucket walk).
__device__ __forceinline__ int prev_ne(const unsigned* __restrict__ bm1,
                                       const unsigned* __restrict__ bm2, int b) {
    if (b == 0) return -1;
    const int p = b - 1;
    unsigned w = bm1[p >> 5] & (~0u >> (31 - (p & 31)));
    if (w) return (p & ~31) | (31 - __clz(w));
    const int W = (p >> 5) - 1;
    if (W < 0) return -1;
    int j = W >> 5;
    unsigned w2 = bm2[j] & (~0u >> (31 - (W & 31)));
    while (!w2 && --j >= 0) w2 = bm2[j];
    if (!w2) return -1;
    const int Wp = (j << 5) | (31 - __clz(w2));
    return (Wp << 5) | (31 - __clz(bm1[Wp]));
}
__device__ __forceinline__ int next_ne(const unsigned* __restrict__ bm1,
                                       const unsigned* __restrict__ bm2, int b) {
    if (b >= BKT - 1) return -1;
    const int p = b + 1;
    unsigned w = bm1[p >> 5] & (~0u << (p & 31));
    if (w) return (p & ~31) | (__ffs(w) - 1);
    const int W = (p >> 5) + 1;
    if (W > 1023) return -1;
    int j = W >> 5;
    unsigned w2 = bm2[j] & (~0u << (W & 31));
    while (!w2 && ++j < 32) w2 = bm2[j];
    if (!w2) return -1;
    const int Wp = (j << 5) | (__ffs(w2) - 1);
    return (Wp << 5) | (__ffs(bm1[Wp]) - 1);
}

// Min |v - e| over one bucket's slot line: 4 independent uint4 loads,
// count-masked in registers. Slots beyond cnt are garbage but excluded.
__device__ __forceinline__ float scan_bucket(const unsigned* __restrict__ cnt,
                                             const float* __restrict__ slots,
                                             int side, int b, float v, float best) {
    const unsigned c = min(cnt[b], (unsigned)SLOTS);
    const float4* sl4 = (const float4*)(slots + ((size_t)(side * BKT + b)) * SLOTS);
    float e[SLOTS];
    *(float4*)(e + 0)  = sl4[0];
    *(float4*)(e + 4)  = sl4[1];
    *(float4*)(e + 8)  = sl4[2];
    *(float4*)(e + 12) = sl4[3];
#pragma unroll
    for (int j = 0; j < SLOTS; ++j) {
        const float d = fabsf(v - e[j]);
        best = ((unsigned)j < c) ? fminf(best, d) : best;
    }
    return best;
}

// ---- query one element (v already in register). Exactness: candidates =
// own bucket + nearest nonempty bucket below + nearest nonempty bucket above
// + full overflow list. The value-order predecessor/successor of v are
// always in this set (bucket map monotone), every candidate is a real
// element, f32 |v-y| rounding is monotone in true distance => min over
// candidates == min over all pairs.
__device__ __forceinline__ float query_point(float v, int side,
                                             const unsigned* __restrict__ ws) {
    const unsigned* cnt = ws + CNT_OFF + side * BKT;
    const unsigned* bm1 = ws + BM1_OFF + side * 1024;
    const unsigned* bm2 = ws + BM2_OFF + side * 32;
    const float* slots = (const float*)(ws + SLOTS_OFF);
    const int b = bucket_of(v);

    float best = scan_bucket(cnt, slots, side, b, v, FLT_MAX);
    const int bp = prev_ne(bm1, bm2, b);
    if (bp >= 0) best = scan_bucket(cnt, slots, side, bp, v, best);
    const int bn = next_ne(bm1, bm2, b);
    if (bn >= 0) best = scan_bucket(cnt, slots, side, bn, v, best);

    const unsigned oc = min(ws[OVC_OFF + side], (unsigned)OVCAP);
    const float* ovf = (const float*)(ws + OVF_OFF) + side * OVCAP;
    for (unsigned k = 0; k < oc; ++k)
        best = fminf(best, fabsf(v - ovf[k]));
    return best;
}

// ---- fused build + tight grid barrier + query + last-block fold ----------
// Barrier mechanism == R5's proven DONE pattern (release fence -> agent
// atomic -> acquire fence), just used grid-wide: every XCD that hosts
// blocks writes back its dirty L2 lines (threadfence) before arriving;
// after the spin, threadfence invalidates stale clean lines so post-barrier
// plain loads fetch the merged data from LLC. NOT cg::grid.sync (R4: ~13us
// each from sleep-granular spin + coop-launch overhead).
// Requires all blocks co-resident: launcher guarantees grid <= 256 blocks
// (256 CUs, 20 VGPR, no LDS) on this path.
__global__ __launch_bounds__(TPB) void
chamfer_fused(const float* __restrict__ x, const float* __restrict__ y,
              int n, int m, unsigned* __restrict__ ws,
              double* __restrict__ bsums, float* __restrict__ out) {
    const int tid = blockIdx.x * TPB + (int)threadIdx.x;
    const int total = n + m;
    const unsigned nb = gridDim.x;

    // ---- phase B: build (thread tid owns element tid; v stays in register)
    const bool live = tid < total;
    const bool isx = live && (tid < n);
    float v = 0.0f;
    if (live) {
        v = isx ? x[tid] : y[tid - n];
        build_point(v, isx ? 0 : 1, ws);
    }

    // ---- tight grid barrier ----
    __syncthreads();
    if (threadIdx.x == 0) {
        __threadfence();                           // release: wb dirty L2 lines
        atomicAdd(ws + ARR_OFF, 1u);
        while (__hip_atomic_load(ws + ARR_OFF, __ATOMIC_RELAXED,
                                 __HIP_MEMORY_SCOPE_AGENT) < nb) {
            __builtin_amdgcn_s_sleep(1);
        }
    }
    __syncthreads();
    __threadfence();                               // acquire: inv stale lines

    // ---- phase Q: query own element, deterministic block partial ----
    double sx = 0.0, sy = 0.0;
    if (live) {
        const float best = query_point(v, isx ? 1 : 0, ws);
        if (isx) sx = (double)best; else sy = (double)best;
    }
    for (int off = 32; off > 0; off >>= 1) {
        sx += __shfl_down(sx, off);
        sy += __shfl_down(sy, off);
    }
    __shared__ double wsx[TPB / 64], wsy[TPB / 64];
    const int w = threadIdx.x >> 6;
    if ((threadIdx.x & 63) == 0) { wsx[w] = sx; wsy[w] = sy; }
    __syncthreads();

    __shared__ bool s_last;
    if (threadIdx.x == 0) {
        double tx = 0.0, ty = 0.0;
#pragma unroll
        for (int i = 0; i < TPB / 64; ++i) { tx += wsx[i]; ty += wsy[i]; }
        bsums[2 * blockIdx.x] = tx;
        bsums[2 * blockIdx.x + 1] = ty;
        __threadfence();                           // release partials
        const unsigned old = atomicAdd(ws + DONE_OFF, 1u);
        s_last = (old == nb - 1);
    }
    __syncthreads();
    if (!s_last) return;

    // last block: acquire + fold partials in fixed order (== old final)
    __threadfence();
    double fx = 0.0, fy = 0.0;
    for (int i = (int)threadIdx.x; i < (int)nb; i += TPB) {
        fx += bsums[2 * i];
        fy += bsums[2 * i + 1];
    }
    for (int off = 32; off > 0; off >>= 1) {
        fx += __shfl_down(fx, off);
        fy += __shfl_down(fy, off);
    }
    __shared__ double lsx[TPB / 64], lsy[TPB / 64];
    const int wave = threadIdx.x >> 6;
    if ((threadIdx.x & 63) == 0) { lsx[wave] = fx; lsy[wave] = fy; }
    __syncthreads();
    if (threadIdx.x == 0) {
        double tx = 0.0, ty = 0.0;
#pragma unroll
        for (int w2 = 0; w2 < TPB / 64; ++w2) { tx += lsx[w2]; ty += lsy[w2]; }
        const double a = (double)ALPHA;
        out[0] = (float)(a * tx / (double)n + (1.0 - a) * ty / (double)m);
    }
}

// ---- fallback pipeline (nb > 256: barrier residency not guaranteed) ------
__global__ __launch_bounds__(TPB) void
chamfer_build(const float* __restrict__ x, const float* __restrict__ y,
              int n, int m, unsigned* __restrict__ ws) {
    const int i = blockIdx.x * TPB + threadIdx.x;
    if (i >= n + m) return;
    const bool isx = i < n;
    const float v = isx ? x[i] : y[i - n];
    build_point(v, isx ? 0 : 1, ws);
}

__global__ __launch_bounds__(TPB) void
chamfer_query(const float* __restrict__ x, const float* __restrict__ y,
              int n, int m, unsigned* __restrict__ ws,
              double* __restrict__ bsums, float* __restrict__ out) {
    const int q = blockIdx.x * TPB + threadIdx.x;
    const int total = n + m;
    double sx = 0.0, sy = 0.0;
    if (q < total) {
        const bool isx = q < n;
        const float v = isx ? x[q] : y[q - n];
        const float best = query_point(v, isx ? 1 : 0, ws);
        if (isx) sx = (double)best; else sy = (double)best;
    }
    for (int off = 32; off > 0; off >>= 1) {
        sx += __shfl_down(sx, off);
        sy += __shfl_down(sy, off);
    }
    __shared__ double wsx[TPB / 64], wsy[TPB / 64];
    const int w = threadIdx.x >> 6;
    if ((threadIdx.x & 63) == 0) { wsx[w] = sx; wsy[w] = sy; }
    __syncthreads();
    __shared__ bool s_last;
    if (threadIdx.x == 0) {
        double tx = 0.0, ty = 0.0;
#pragma unroll
        for (int i = 0; i < TPB / 64; ++i) { tx += wsx[i]; ty += wsy[i]; }
        bsums[2 * blockIdx.x] = tx;
        bsums[2 * blockIdx.x + 1] = ty;
        __threadfence();
        const unsigned old = atomicAdd(ws + DONE_OFF, 1u);
        s_last = (old == gridDim.x - 1);
    }
    __syncthreads();
    if (!s_last) return;
    __threadfence();
    const int nb = (int)gridDim.x;
    double fx = 0.0, fy = 0.0;
    for (int i = (int)threadIdx.x; i < nb; i += TPB) {
        fx += bsums[2 * i];
        fy += bsums[2 * i + 1];
    }
    for (int off = 32; off > 0; off >>= 1) {
        fx += __shfl_down(fx, off);
        fy += __shfl_down(fy, off);
    }
    __shared__ double lsx[TPB / 64], lsy[TPB / 64];
    const int wave = threadIdx.x >> 6;
    if ((threadIdx.x & 63) == 0) { lsx[wave] = fx; lsy[wave] = fy; }
    __syncthreads();
    if (threadIdx.x == 0) {
        double tx = 0.0, ty = 0.0;
        for (int w2 = 0; w2 < TPB / 64; ++w2) { tx += lsx[w2]; ty += lsy[w2]; }
        const double a = (double)ALPHA;
        out[0] = (float)(a * tx / (double)n + (1.0 - a) * ty / (double)m);
    }
}

extern "C" void kernel_launch(void* const* d_in, const int* in_sizes, int n_in,
                              void* d_out, int out_size, void* d_ws, size_t ws_size,
                              hipStream_t stream) {
    const float* x = (const float*)d_in[0];
    const float* y = (const float*)d_in[1];
    const int n = in_sizes[0];
    const int m = in_sizes[1];
    float* out = (float*)d_out;
    const int total = n + m;

    unsigned* ws = (unsigned*)d_ws;
    const size_t meta_bytes = (size_t)(OVF_OFF + 2 * OVCAP) * sizeof(unsigned);
    const size_t meta_al = (meta_bytes + 255) & ~(size_t)255;
    double* bsums = (double*)((char*)d_ws + meta_al);

    const int nb = (total + TPB - 1) / TPB;   // 128 blocks for 32768 points

    hipMemsetAsync(ws, 0, (size_t)ZERO_WORDS * sizeof(unsigned), stream);
    if (nb <= 256) {
        // all blocks co-resident (256 CUs, tiny footprint): fused path
        chamfer_fused<<<nb, TPB, 0, stream>>>(x, y, n, m, ws, bsums, out);
    } else {
        chamfer_build<<<nb, TPB, 0, stream>>>(x, y, n, m, ws);
        chamfer_query<<<nb, TPB, 0, stream>>>(x, y, n, m, ws, bsums, out);
    }
}

// Round 7
// 80.183 us; speedup vs baseline: 1.0493x; 1.0493x over previous
//
#include <hip/hip_runtime.h>
#include <cfloat>

#define TPB 256
#define NBLK 128                  // build blocks; block k owns GB global buckets
#define BKT 32768                 // buckets per side (2048 per unit over [-8,8))
#define GBT (2 * BKT)             // 65536 global buckets, side-major
#define GB (GBT / NBLK)           // 512 buckets per build block
#define SLOTS 16                  // floats per bucket = one 64B line
#define RLO -8.0f
#define RSCALE (BKT / 16.0f)      // exact power of two
#define ALPHA 0.5f

static_assert(2 * NBLK == TPB, "ovfc staging assumes one entry per query thread");

// ---- workspace layout (uint words). NOTHING is pre-zeroed: every word is
// either owner-written every invocation (cnt/bm1/bm2h/ovfc/done/bsums) or
// read-gated by an owner-written count (slots/ovf). Poison-safe by
// construction -> the hipMemsetAsync dispatch is gone.
#define CNT_OFF   0                           // cnt[GBT]
#define BM1_OFF   (GBT)                       // GBT/32 = 2048 words
#define BM2H_OFF  (BM1_OFF + GBT / 32)        // NBLK words (per-block halves)
#define OVFC_OFF  (BM2H_OFF + NBLK)           // 2*NBLK words (per block, per side)
#define DONE_OFF  (OVFC_OFF + 2 * NBLK)       // 1 word (written 0 by build blk 0)
#define SLOTS_OFF (((DONE_OFF + 1) + 15) & ~15)   // floats, GBT*SLOTS, 64B-aligned
#define OVF_OFF   (SLOTS_OFF + GBT * SLOTS)       // floats, 2*NBLK*total (runtime)

// Monotone non-decreasing (fl(v+8) monotone, *2048 exact pow2, trunc+clamp
// monotone) => bucket(u) < bucket(w) implies u < w.
__device__ __forceinline__ int bucket_of(float v) {
    int b = (int)((v - RLO) * RSCALE);
    return min(max(b, 0), BKT - 1);
}

// ---- build: bucket-partitioned, zero-init-free, device-atomic-free -------
// Block k zeroes its LDS counters, streams ALL input (128 KB; L2-resident
// broadcast across blocks), catches elements whose global bucket falls in
// [k*GB,(k+1)*GB) via LDS atomicAdd (contention trivial), then plain-writes
// its cnt / bm1 / bm2-half slices. R2 lesson (contended device atomicOr =
// 90+ us) and R4/R6 lesson (grid-wide sync = 12+ us) both avoided: the only
// cross-block coordination is the dispatch boundary.
__global__ __launch_bounds__(TPB) void
chamfer_build(const float* __restrict__ x, const float* __restrict__ y,
              int n, int m, unsigned* __restrict__ ws) {
    __shared__ unsigned lcnt[GB];
    __shared__ unsigned lbm1[GB / 32];
    __shared__ unsigned lovf[2];
    const int k = blockIdx.x;
    const int base = k * GB;
    const int total = n + m;
    float* const slots = (float*)(ws + SLOTS_OFF);
    float* const ovf0 = (float*)(ws + OVF_OFF) + (size_t)(2 * k + 0) * total;
    float* const ovf1 = (float*)(ws + OVF_OFF) + (size_t)(2 * k + 1) * total;

    for (int i = threadIdx.x; i < GB; i += TPB) lcnt[i] = 0;
    if (threadIdx.x < 2) lovf[threadIdx.x] = 0;
    if (k == 0 && threadIdx.x == 0) ws[DONE_OFF] = 0;   // for query's fold
    __syncthreads();

    // Single pass: position comes from the same LDS atomicAdd as the count;
    // overflow is UNORDERED (query scans the whole list) so no scan needed.
    auto catch_elem = [&](float v, int side, float* ovfp) {
        const int lb = side * BKT + bucket_of(v) - base;
        if ((unsigned)lb < (unsigned)GB) {
            const unsigned pos = atomicAdd(&lcnt[lb], 1u);
            if (pos < SLOTS)
                slots[(size_t)(base + lb) * SLOTS + pos] = v;
            else
                ovfp[atomicAdd(&lovf[side], 1u)] = v;   // exact: capacity = total
        }
    };
    {
        const int n4 = n >> 2;
        const float4* x4 = (const float4*)x;
        for (int i = threadIdx.x; i < n4; i += TPB) {
            const float4 a = x4[i];
            catch_elem(a.x, 0, ovf0); catch_elem(a.y, 0, ovf0);
            catch_elem(a.z, 0, ovf0); catch_elem(a.w, 0, ovf0);
        }
        for (int i = (n4 << 2) + threadIdx.x; i < n; i += TPB)
            catch_elem(x[i], 0, ovf0);
    }
    {
        const int m4 = m >> 2;
        const float4* y4 = (const float4*)y;
        for (int i = threadIdx.x; i < m4; i += TPB) {
            const float4 a = y4[i];
            catch_elem(a.x, 1, ovf1); catch_elem(a.y, 1, ovf1);
            catch_elem(a.z, 1, ovf1); catch_elem(a.w, 1, ovf1);
        }
        for (int i = (m4 << 2) + threadIdx.x; i < m; i += TPB)
            catch_elem(y[i], 1, ovf1);
    }
    __syncthreads();

    // owner write-out (plain stores; coalesced)
    for (int i = threadIdx.x; i < GB; i += TPB) ws[CNT_OFF + base + i] = lcnt[i];
    if (threadIdx.x < GB / 32) {
        const int w = threadIdx.x;
        unsigned bits = 0;
#pragma unroll
        for (int j = 0; j < 32; ++j)
            if (lcnt[w * 32 + j]) bits |= 1u << j;
        lbm1[w] = bits;
        ws[BM1_OFF + (base >> 5) + w] = bits;
    }
    if (threadIdx.x < 2) ws[OVFC_OFF + 2 * k + threadIdx.x] = lovf[threadIdx.x];
    __syncthreads();
    if (threadIdx.x == 0) {
        // block covers 16 bm1 words = half a bm2 word; query ORs the halves
        unsigned bits = 0;
#pragma unroll
        for (int w = 0; w < GB / 32; ++w)
            if (lbm1[w]) bits |= 1u << w;
        ws[BM2H_OFF + k] = bits << ((k & 1) << 4);
    }
}

// Previous/next nonempty bucket via 2-level bitmap (LDS-staged, no walk).
__device__ __forceinline__ int prev_ne(const unsigned* bm1, const unsigned* bm2,
                                       int b) {
    if (b == 0) return -1;
    const int p = b - 1;
    unsigned w = bm1[p >> 5] & (~0u >> (31 - (p & 31)));
    if (w) return (p & ~31) | (31 - __clz(w));
    const int W = (p >> 5) - 1;
    if (W < 0) return -1;
    int j = W >> 5;
    unsigned w2 = bm2[j] & (~0u >> (31 - (W & 31)));
    while (!w2 && --j >= 0) w2 = bm2[j];
    if (!w2) return -1;
    const int Wp = (j << 5) | (31 - __clz(w2));
    return (Wp << 5) | (31 - __clz(bm1[Wp]));
}
__device__ __forceinline__ int next_ne(const unsigned* bm1, const unsigned* bm2,
                                       int b) {
    if (b >= BKT - 1) return -1;
    const int p = b + 1;
    unsigned w = bm1[p >> 5] & (~0u << (p & 31));
    if (w) return (p & ~31) | (__ffs(w) - 1);
    const int W = (p >> 5) + 1;
    if (W > 1023) return -1;
    int j = W >> 5;
    unsigned w2 = bm2[j] & (~0u << (W & 31));
    while (!w2 && ++j < 32) w2 = bm2[j];
    if (!w2) return -1;
    const int Wp = (j << 5) | (__ffs(w2) - 1);
    return (Wp << 5) | (__ffs(bm1[Wp]) - 1);
}

// Min |v - e| over one bucket's slot line: 4 independent uint4 loads,
// count-masked in registers. Slots beyond cnt are poison but excluded.
__device__ __forceinline__ float scan_bucket(const unsigned* __restrict__ cnt,
                                             const float* __restrict__ slots,
                                             int gb, float v, float best) {
    const unsigned c = min(cnt[gb], (unsigned)SLOTS);
    const float4* sl4 = (const float4*)(slots + (size_t)gb * SLOTS);
    float e[SLOTS];
    *(float4*)(e + 0)  = sl4[0];
    *(float4*)(e + 4)  = sl4[1];
    *(float4*)(e + 8)  = sl4[2];
    *(float4*)(e + 12) = sl4[3];
#pragma unroll
    for (int j = 0; j < SLOTS; ++j) {
        const float d = fabsf(v - e[j]);
        best = ((unsigned)j < c) ? fminf(best, d) : best;
    }
    return best;
}

// ---- query + fused final (R5 structure; bitmap now LDS-staged) -----------
// Exactness: candidates = own bucket + nearest nonempty bucket below +
// nearest nonempty bucket above + full overflow list of the side. The
// value-order predecessor/successor of v are always in this set (bucket map
// monotone), every candidate is a real element, f32 |v-y| rounding is
// monotone in true distance => min over candidates == min over all pairs.
// Fixed reduction order == R5 => bitwise-identical result.
__global__ __launch_bounds__(TPB) void
chamfer_query(const float* __restrict__ x, const float* __restrict__ y,
              int n, int m, unsigned* __restrict__ ws,
              double* __restrict__ bsums, float* __restrict__ out) {
    __shared__ unsigned s_bm1[GBT / 32];      // 8 KB
    __shared__ unsigned s_bm2[64];
    __shared__ unsigned s_ovfc[2 * NBLK];     // == TPB entries
    __shared__ unsigned s_has_ovf;

    const int lt = (int)threadIdx.x;
    for (int i = lt; i < GBT / 32; i += TPB) s_bm1[i] = ws[BM1_OFF + i];
    if (lt < 64) s_bm2[lt] = ws[BM2H_OFF + 2 * lt] | ws[BM2H_OFF + 2 * lt + 1];
    s_ovfc[lt] = ws[OVFC_OFF + lt];
    if (lt == 0) s_has_ovf = 0;
    __syncthreads();
    if (s_ovfc[lt]) atomicOr(&s_has_ovf, 1u); // expected never taken
    __syncthreads();

    const int q = blockIdx.x * TPB + lt;
    const int total = n + m;
    double sx = 0.0, sy = 0.0;
    if (q < total) {
        const bool isx = q < n;
        const float v = isx ? x[q] : y[q - n];
        const int side = isx ? 1 : 0;         // search the OTHER side
        const unsigned* cnt = ws + CNT_OFF;
        const unsigned* bm1 = s_bm1 + side * (BKT / 32);
        const unsigned* bm2 = s_bm2 + side * 32;
        const float* slots = (const float*)(ws + SLOTS_OFF);
        const int b = bucket_of(v);

        float best = scan_bucket(cnt, slots, side * BKT + b, v, FLT_MAX);
        const int bp = prev_ne(bm1, bm2, b);
        if (bp >= 0) best = scan_bucket(cnt, slots, side * BKT + bp, v, best);
        const int bn = next_ne(bm1, bm2, b);
        if (bn >= 0) best = scan_bucket(cnt, slots, side * BKT + bn, v, best);

        if (s_has_ovf) {                      // correctness path, ~never taken
            const float* ovfbase = (const float*)(ws + OVF_OFF);
            for (int e = side; e < 2 * NBLK; e += 2) {
                const unsigned c = s_ovfc[e];
                if (c) {
                    const float* op = ovfbase + (size_t)e * total;
                    for (unsigned j = 0; j < c; ++j)
                        best = fminf(best, fabsf(v - op[j]));
                }
            }
        }
        if (isx) sx = (double)best; else sy = (double)best;
    }
    for (int off = 32; off > 0; off >>= 1) {
        sx += __shfl_down(sx, off);
        sy += __shfl_down(sy, off);
    }
    __shared__ double wsx[TPB / 64], wsy[TPB / 64];
    const int w = lt >> 6;
    if ((lt & 63) == 0) { wsx[w] = sx; wsy[w] = sy; }
    __syncthreads();

    __shared__ bool s_last;
    if (lt == 0) {
        double tx = 0.0, ty = 0.0;
#pragma unroll
        for (int i = 0; i < TPB / 64; ++i) { tx += wsx[i]; ty += wsy[i]; }
        bsums[2 * blockIdx.x] = tx;
        bsums[2 * blockIdx.x + 1] = ty;
        __threadfence();                      // release partials
        const unsigned old = atomicAdd(ws + DONE_OFF, 1u);
        s_last = (old == gridDim.x - 1);
    }
    __syncthreads();
    if (!s_last) return;

    __threadfence();                          // acquire partials
    const int nb = (int)gridDim.x;
    double fx = 0.0, fy = 0.0;
    for (int i = lt; i < nb; i += TPB) {
        fx += bsums[2 * i];
        fy += bsums[2 * i + 1];
    }
    for (int off = 32; off > 0; off >>= 1) {
        fx += __shfl_down(fx, off);
        fy += __shfl_down(fy, off);
    }
    __shared__ double lsx[TPB / 64], lsy[TPB / 64];
    const int wave = lt >> 6;
    if ((lt & 63) == 0) { lsx[wave] = fx; lsy[wave] = fy; }
    __syncthreads();
    if (lt == 0) {
        double tx = 0.0, ty = 0.0;
#pragma unroll
        for (int w2 = 0; w2 < TPB / 64; ++w2) { tx += lsx[w2]; ty += lsy[w2]; }
        const double a = (double)ALPHA;
        out[0] = (float)(a * tx / (double)n + (1.0 - a) * ty / (double)m);
    }
}

extern "C" void kernel_launch(void* const* d_in, const int* in_sizes, int n_in,
                              void* d_out, int out_size, void* d_ws, size_t ws_size,
                              hipStream_t stream) {
    const float* x = (const float*)d_in[0];
    const float* y = (const float*)d_in[1];
    const int n = in_sizes[0];
    const int m = in_sizes[1];
    float* out = (float*)d_out;
    const int total = n + m;

    unsigned* ws = (unsigned*)d_ws;
    const size_t ovf_words = (size_t)2 * NBLK * total;      // ~16 MB at 32K pts
    const size_t meta_bytes = (size_t)(OVF_OFF + ovf_words) * sizeof(unsigned);
    const size_t meta_al = (meta_bytes + 255) & ~(size_t)255;
    double* bsums = (double*)((char*)d_ws + meta_al);

    const int nbq = (total + TPB - 1) / TPB;  // 128 blocks

    // no memset: workspace is zero-init-free by construction (see layout)
    chamfer_build<<<NBLK, TPB, 0, stream>>>(x, y, n, m, ws);
    chamfer_query<<<nbq, TPB, 0, stream>>>(x, y, n, m, ws, bsums, out);
}

// Round 8
// 73.353 us; speedup vs baseline: 1.1470x; 1.0931x over previous
//
#include <hip/hip_runtime.h>
#include <cfloat>

#define TPB 256
#define BKT 32768                 // buckets per side (2048 per unit over [-8,8))
#define SLOTS 16                  // floats per bucket = one 64B line
#define OVCAP 4096                // overflow capacity per side (expected 0 used)
#define RLO -8.0f
#define RSCALE (BKT / 16.0f)      // exact power of two
#define ALPHA 0.5f

// ---- workspace layout (uint words) -------------------------------------
// zeroed by ONE hipMemsetAsync (264 KB): cnt | bm1 | bm2 | ovc | done
#define CNT_OFF   0                         // cnt[2*BKT]
#define BM1_OFF   (2 * BKT)                 // 2*1024 words (gated atomicOr)
#define BM2_OFF   (BM1_OFF + 2048)          // 2*32 words (gated atomicOr)
#define OVC_OFF   (BM2_OFF + 64)            // 2 words
#define DONE_OFF  (OVC_OFF + 2)             // 1 word (last-block fold counter)
#define ZERO_WORDS (DONE_OFF + 1)
// not zeroed (reads gated by cnt / ovc):
#define SLOTS_OFF (((ZERO_WORDS) + 63) & ~63)   // floats, 2*BKT*SLOTS (64B-aligned)
#define OVF_OFF   (SLOTS_OFF + 2 * BKT * SLOTS) // floats, 2*OVCAP

// Monotone non-decreasing (fl(v+8) monotone, *2048 exact pow2, trunc+clamp
// monotone) => bucket(u) < bucket(w) implies u < w.
__device__ __forceinline__ int bucket_of(float v) {
    int b = (int)((v - RLO) * RSCALE);
    return min(max(b, 0), BKT - 1);
}

// ---- build: histogram + slot scatter + GATED occupancy bits -------------
// One thread per element (R5-proven: ~3 us). cnt atomicAdd ~4 ops/bucket,
// contention-free. bm1 atomicOr only when pos==0 (<=32 ops/word); bm2
// atomicOr only on bm1 word 0->nonzero (<=32 ops/word). R2 lesson: ungated
// bm2 serialized ~3100 ops on the central word = 90+ us. R7 lesson: the
// "zero-init-free" 128x-redundant-stream build costs MORE than memset+this.
__global__ __launch_bounds__(TPB) void
chamfer_build(const float* __restrict__ x, const float* __restrict__ y,
              int n, int m, unsigned* __restrict__ ws) {
    const int i = blockIdx.x * TPB + threadIdx.x;
    if (i >= n + m) return;
    const bool isx = i < n;
    const int side = isx ? 0 : 1;
    const float v = isx ? x[i] : y[i - n];
    const int b = bucket_of(v);
    const unsigned pos = atomicAdd(ws + CNT_OFF + side * BKT + b, 1u);
    if (pos < SLOTS) {
        ((float*)(ws + SLOTS_OFF))[((size_t)(side * BKT + b)) * SLOTS + pos] = v;
    } else {
        const unsigned o = atomicAdd(ws + OVC_OFF + side, 1u);
        if (o < OVCAP) ((float*)(ws + OVF_OFF))[side * OVCAP + o] = v;
    }
    if (pos == 0) {
        const int W = b >> 5;
        const unsigned old = atomicOr(ws + BM1_OFF + side * 1024 + W, 1u << (b & 31));
        if (old == 0)
            atomicOr(ws + BM2_OFF + side * 32 + (W >> 5), 1u << (W & 31));
    }
}

// Previous/next nonempty bucket via 2-level bitmap (bounded, no bucket walk).
// Pointers may be LDS (query stages the bitmap) -- generic address space.
__device__ __forceinline__ int prev_ne(const unsigned* bm1, const unsigned* bm2,
                                       int b) {
    if (b == 0) return -1;
    const int p = b - 1;
    unsigned w = bm1[p >> 5] & (~0u >> (31 - (p & 31)));
    if (w) return (p & ~31) | (31 - __clz(w));
    const int W = (p >> 5) - 1;
    if (W < 0) return -1;
    int j = W >> 5;
    unsigned w2 = bm2[j] & (~0u >> (31 - (W & 31)));
    while (!w2 && --j >= 0) w2 = bm2[j];
    if (!w2) return -1;
    const int Wp = (j << 5) | (31 - __clz(w2));
    return (Wp << 5) | (31 - __clz(bm1[Wp]));
}
__device__ __forceinline__ int next_ne(const unsigned* bm1, const unsigned* bm2,
                                       int b) {
    if (b >= BKT - 1) return -1;
    const int p = b + 1;
    unsigned w = bm1[p >> 5] & (~0u << (p & 31));
    if (w) return (p & ~31) | (__ffs(w) - 1);
    const int W = (p >> 5) + 1;
    if (W > 1023) return -1;
    int j = W >> 5;
    unsigned w2 = bm2[j] & (~0u << (W & 31));
    while (!w2 && ++j < 32) w2 = bm2[j];
    if (!w2) return -1;
    const int Wp = (j << 5) | (__ffs(w2) - 1);
    return (Wp << 5) | (__ffs(bm1[Wp]) - 1);
}

// Min |v - e| over one bucket's slot line: 4 independent uint4 loads,
// count-masked in registers. Slots beyond cnt are poison but excluded.
__device__ __forceinline__ float scan_bucket(const unsigned* __restrict__ cnt,
                                             const float* __restrict__ slots,
                                             int side, int b, float v, float best) {
    const unsigned c = min(cnt[b], (unsigned)SLOTS);
    const float4* sl4 = (const float4*)(slots + ((size_t)(side * BKT + b)) * SLOTS);
    float e[SLOTS];
    *(float4*)(e + 0)  = sl4[0];
    *(float4*)(e + 4)  = sl4[1];
    *(float4*)(e + 8)  = sl4[2];
    *(float4*)(e + 12) = sl4[3];
#pragma unroll
    for (int j = 0; j < SLOTS; ++j) {
        const float d = fabsf(v - e[j]);
        best = ((unsigned)j < c) ? fminf(best, d) : best;
    }
    return best;
}

// ---- query + fused final (R5 structure + LDS-staged bitmap) --------------
// Exactness: candidates = own bucket + nearest nonempty bucket below +
// nearest nonempty bucket above + full overflow list. The value-order
// predecessor/successor of v are always in this set (bucket map monotone),
// every candidate is a real element, f32 |v-y| rounding is monotone in true
// distance => min over candidates == min over all pairs. Fixed reduction
// order identical to R5 => bitwise-identical result (absmax 0).
__global__ __launch_bounds__(TPB) void
chamfer_query(const float* __restrict__ x, const float* __restrict__ y,
              int n, int m, unsigned* __restrict__ ws,
              double* __restrict__ bsums, float* __restrict__ out) {
    __shared__ unsigned s_bm1[2048];          // 8 KB: both sides' bm1
    __shared__ unsigned s_bm2[64];            // both sides' bm2
    const int lt = (int)threadIdx.x;
#pragma unroll
    for (int k = 0; k < 2048 / TPB; ++k)
        s_bm1[lt + k * TPB] = ws[BM1_OFF + lt + k * TPB];
    if (lt < 64) s_bm2[lt] = ws[BM2_OFF + lt];
    __syncthreads();

    const int q = blockIdx.x * TPB + lt;
    const int total = n + m;
    double sx = 0.0, sy = 0.0;
    if (q < total) {
        const bool isx = q < n;
        const float v = isx ? x[q] : y[q - n];
        const int side = isx ? 1 : 0;            // search the OTHER side
        const unsigned* cnt = ws + CNT_OFF + side * BKT;
        const unsigned* bm1 = s_bm1 + side * 1024;
        const unsigned* bm2 = s_bm2 + side * 32;
        const float* slots = (const float*)(ws + SLOTS_OFF);
        const int b = bucket_of(v);

        float best = scan_bucket(cnt, slots, side, b, v, FLT_MAX);
        const int bp = prev_ne(bm1, bm2, b);
        if (bp >= 0) best = scan_bucket(cnt, slots, side, bp, v, best);
        const int bn = next_ne(bm1, bm2, b);
        if (bn >= 0) best = scan_bucket(cnt, slots, side, bn, v, best);

        const unsigned oc = min(ws[OVC_OFF + side], (unsigned)OVCAP);
        const float* ovf = (const float*)(ws + OVF_OFF) + side * OVCAP;
        for (unsigned k = 0; k < oc; ++k)
            best = fminf(best, fabsf(v - ovf[k]));

        if (isx) sx = (double)best; else sy = (double)best;
    }
    for (int off = 32; off > 0; off >>= 1) {
        sx += __shfl_down(sx, off);
        sy += __shfl_down(sy, off);
    }
    __shared__ double wsx[TPB / 64], wsy[TPB / 64];
    const int w = lt >> 6;
    if ((lt & 63) == 0) { wsx[w] = sx; wsy[w] = sy; }
    __syncthreads();

    __shared__ bool s_last;
    if (lt == 0) {
        double tx = 0.0, ty = 0.0;
#pragma unroll
        for (int i = 0; i < TPB / 64; ++i) { tx += wsx[i]; ty += wsy[i]; }
        bsums[2 * blockIdx.x] = tx;
        bsums[2 * blockIdx.x + 1] = ty;
        __threadfence();                          // release partials
        const unsigned old = atomicAdd(ws + DONE_OFF, 1u);
        s_last = (old == gridDim.x - 1);
    }
    __syncthreads();
    if (!s_last) return;

    // last block: acquire + fold partials in fixed order (== R5 final)
    __threadfence();
    const int nb = (int)gridDim.x;
    double fx = 0.0, fy = 0.0;
    for (int i = lt; i < nb; i += TPB) {
        fx += bsums[2 * i];
        fy += bsums[2 * i + 1];
    }
    for (int off = 32; off > 0; off >>= 1) {
        fx += __shfl_down(fx, off);
        fy += __shfl_down(fy, off);
    }
    __shared__ double lsx[TPB / 64], lsy[TPB / 64];
    const int wave = lt >> 6;
    if ((lt & 63) == 0) { lsx[wave] = fx; lsy[wave] = fy; }
    __syncthreads();
    if (lt == 0) {
        double tx = 0.0, ty = 0.0;
#pragma unroll
        for (int w2 = 0; w2 < TPB / 64; ++w2) { tx += lsx[w2]; ty += lsy[w2]; }
        const double a = (double)ALPHA;
        out[0] = (float)(a * tx / (double)n + (1.0 - a) * ty / (double)m);
    }
}

extern "C" void kernel_launch(void* const* d_in, const int* in_sizes, int n_in,
                              void* d_out, int out_size, void* d_ws, size_t ws_size,
                              hipStream_t stream) {
    const float* x = (const float*)d_in[0];
    const float* y = (const float*)d_in[1];
    const int n = in_sizes[0];
    const int m = in_sizes[1];
    float* out = (float*)d_out;
    const int total = n + m;

    unsigned* ws = (unsigned*)d_ws;
    const size_t meta_bytes = (size_t)(OVF_OFF + 2 * OVCAP) * sizeof(unsigned);
    const size_t meta_al = (meta_bytes + 255) & ~(size_t)255;
    double* bsums = (double*)((char*)d_ws + meta_al);

    const int nb = (total + TPB - 1) / TPB;   // 128 blocks for 32768 points

    hipMemsetAsync(ws, 0, (size_t)ZERO_WORDS * sizeof(unsigned), stream);
    chamfer_build<<<nb, TPB, 0, stream>>>(x, y, n, m, ws);
    chamfer_query<<<nb, TPB, 0, stream>>>(x, y, n, m, ws, bsums, out);
}